// Round 7
// baseline (3186.869 us; speedup 1.0000x reference)
//
#include <hip/hip_runtime.h>

#define ATOM  14
#define BOND  3
#define INNER 20
#define HID   34
#define REC   20
#define OHID  25
#define NN    1048576
#define NE    983040
#define NG    16384
#define NBIN  16

#define NB    1024
#define NT    256
#define GT    (NB*NT)        // 262144
#define CHUNK (NN/NB)        // 1024 positions per block for row scan
#define SE    (CHUNK/NT)     // 4
#define SB    (NB/NT)        // 4 block-sums per thread in scanB

__device__ __forceinline__ float leaky(float x) { return x >= 0.f ? x : 0.01f * x; }

// grid-wide barrier: device-scope counter + fences (cross-XCD safe)
__device__ __forceinline__ void gbar(int* bar, int goal) {
    __syncthreads();
    if (threadIdx.x == 0) {
        __threadfence();   // release
        __hip_atomic_fetch_add(bar, 1, __ATOMIC_RELEASE, __HIP_MEMORY_SCOPE_AGENT);
        while (__hip_atomic_load(bar, __ATOMIC_RELAXED, __HIP_MEMORY_SCOPE_AGENT) < goal)
            __builtin_amdgcn_s_sleep(2);
        __threadfence();   // acquire
    }
    __syncthreads();
}

__global__ void k_zero_bar(int* bar) {
    if (threadIdx.x == 0 && blockIdx.x == 0) *bar = 0;
}

__global__ __launch_bounds__(NT, 4) void k_fused(
    const float* __restrict__ atom, const float* __restrict__ bond,
    const int* __restrict__ parent, const int* __restrict__ child,
    const int* __restrict__ depth, const int* __restrict__ gid,
    const float* __restrict__ isr,
    const float* __restrict__ iw, const float* __restrict__ ib,
    const float* __restrict__ nw1, const float* __restrict__ nb1,
    const float* __restrict__ nw2, const float* __restrict__ nb2,
    const float* __restrict__ l0w1, const float* __restrict__ l0b1,
    const float* __restrict__ l0w2, const float* __restrict__ l0b2,
    const float* __restrict__ ow1, const float* __restrict__ ob1,
    const float* __restrict__ ow2, const float* __restrict__ ob2,
    float* __restrict__ out,
    float* msg_s, float* g, float* bond_s,
    int* node_list, int* inv, int* pp_s, int* groot_s,
    int* row_ptr, int* cnt_i, int* adjc, int* bsum, int* boff,
    int* cnt16, int* off, int* cur, int* bar)
{
    __shared__ int sh[NT];
    __shared__ int soff[NBIN + 1];
    __shared__ int lh[NBIN];
    __shared__ int lbase[NBIN];
    const int t = threadIdx.x;
    const int tid = blockIdx.x * NT + t;
    int ep = 0;
    const volatile int* voff = off;

    // ---- P0: init ----
    for (int i = tid; i < NN; i += GT) { cnt_i[i] = 0; pp_s[i] = -1; }
    for (int i = tid; i < NG * REC; i += GT) g[i] = 0.f;
    if (tid < NBIN) { cnt16[tid << 4] = 0; cur[tid << 4] = 0; }
    gbar(bar, NB * ++ep);

    // ---- P1: child-count atomics + depth histogram ----
    if (t < NBIN) lh[t] = 0;
    __syncthreads();
    for (int e = tid; e < NE; e += GT) atomicAdd(&cnt_i[parent[e]], 1);
    for (int i = tid; i < NN; i += GT) atomicAdd(&lh[depth[i]], 1);
    __syncthreads();
    if (t < NBIN && lh[t]) atomicAdd(&cnt16[t << 4], lh[t]);
    gbar(bar, NB * ++ep);

    // ---- P2: counting sort by depth (per-block redundant bin scan) ----
    if (t == 0) {
        int s = 0;
        for (int d = 0; d < NBIN; ++d) { soff[d] = s; s += cnt16[d << 4]; }
        soff[NBIN] = s;
        if (blockIdx.x == 0)
            for (int d = 0; d <= NBIN; ++d) off[d] = soff[d];
    }
    __syncthreads();
    for (int chunk = blockIdx.x; chunk < NN / NT; chunk += NB) {
        __syncthreads();
        if (t < NBIN) lh[t] = 0;
        __syncthreads();
        int i = chunk * NT + t;
        int b = depth[i];
        int r = atomicAdd(&lh[b], 1);
        __syncthreads();
        if (t < NBIN && lh[t]) lbase[t] = atomicAdd(&cur[t << 4], lh[t]) + soff[t];
        __syncthreads();
        int pos = lbase[b] + r;
        node_list[pos] = i;
        inv[i] = pos;
        groot_s[pos] = (isr[i] != 0.f) ? gid[i] : -1;
    }
    gbar(bar, NB * ++ep);

    // ---- P3: edge prep + per-chunk exclusive scan of child counts ----
    for (int e = tid; e < NE; e += GT) {
        int cpos = inv[child[e]];
        pp_s[cpos] = inv[parent[e]];
        bond_s[(size_t)cpos * BOND + 0] = bond[(size_t)e * BOND + 0];
        bond_s[(size_t)cpos * BOND + 1] = bond[(size_t)e * BOND + 1];
        bond_s[(size_t)cpos * BOND + 2] = bond[(size_t)e * BOND + 2];
    }
    {
        int base0 = blockIdx.x * CHUNK + t * SE;
        int v[SE]; int sum = 0;
        #pragma unroll
        for (int k = 0; k < SE; ++k) { v[k] = cnt_i[node_list[base0 + k]]; sum += v[k]; }
        __syncthreads();
        sh[t] = sum;
        __syncthreads();
        for (int ofs = 1; ofs < NT; ofs <<= 1) {
            int x = (t >= ofs) ? sh[t - ofs] : 0;
            __syncthreads();
            sh[t] += x;
            __syncthreads();
        }
        int run = sh[t] - sum;
        #pragma unroll
        for (int k = 0; k < SE; ++k) { row_ptr[base0 + k] = run; run += v[k]; }
        if (t == NT - 1) bsum[blockIdx.x] = sh[t];
    }
    gbar(bar, NB * ++ep);

    // ---- P4: block0 scans block sums; all blocks zero rank counters (reuse inv) ----
    if (blockIdx.x == 0) {
        int v[SB]; int p = 0;
        #pragma unroll
        for (int k = 0; k < SB; ++k) { v[k] = bsum[t * SB + k]; p += v[k]; }
        sh[t] = p;
        __syncthreads();
        for (int ofs = 1; ofs < NT; ofs <<= 1) {
            int x = (t >= ofs) ? sh[t - ofs] : 0;
            __syncthreads();
            sh[t] += x;
            __syncthreads();
        }
        int run = sh[t] - p;
        #pragma unroll
        for (int k = 0; k < SB; ++k) { boff[t * SB + k] = run; run += v[k]; }
        if (t == NT - 1) { row_ptr[NN] = sh[t]; boff[NB] = 0; }
    }
    for (int i = tid; i < NN; i += GT) inv[i] = 0;
    gbar(bar, NB * ++ep);

    // ---- P5: CSR child lists ----
    for (int pos = tid; pos < NN; pos += GT) {
        int pp = pp_s[pos];
        if (pp >= 0) {
            int r = atomicAdd(&inv[pp], 1);
            adjc[row_ptr[pp] + boff[pp >> 10] + r] = pos;
        }
    }
    gbar(bar, NB * ++ep);

    // ---- P6..P21: levels d = 15..0 (leaf via net0, internal via gather+net) ----
    for (int d = NBIN - 1; d >= 0; --d) {
        int q0 = voff[d], q1 = voff[d + 1];
        for (int pos = q0 + tid; pos < q1; pos += GT) {
            // independent loads first
            int i = node_list[pos];
            int pp = pp_s[pos];
            int gr = groot_s[pos];
            int rp0 = row_ptr[pos] + boff[pos >> 10];
            int rp1 = row_ptr[pos + 1] + boff[(pos + 1) >> 10];
            const float2* a2 = (const float2*)(atom + (size_t)i * ATOM);
            float a[ATOM];
            #pragma unroll
            for (int k = 0; k < 7; ++k) { float2 v = a2[k]; a[2*k] = v.x; a[2*k+1] = v.y; }
            int n = rp1 - rp0;
            float o[REC];
            if (n == 0) {
                // ---- leaf: net0 MLP ----
                float hid[HID];
                #pragma unroll
                for (int j = 0; j < HID; ++j) hid[j] = l0b1[j];
                for (int k = 0; k < ATOM; ++k) {
                    float ak = a[k];
                    #pragma unroll
                    for (int j = 0; j < HID; ++j) hid[j] += ak * l0w1[k * HID + j];
                }
                #pragma unroll
                for (int j = 0; j < HID; ++j) hid[j] = leaky(hid[j]);
                #pragma unroll
                for (int j = 0; j < REC; ++j) o[j] = l0b2[j];
                for (int k = 0; k < HID; ++k) {
                    float hk = hid[k];
                    #pragma unroll
                    for (int j = 0; j < REC; ++j) o[j] += hk * l0w2[k * REC + j];
                }
            } else {
                // ---- internal: gather children msgs (4-wide clamped), net MLP ----
                float isum[INNER];
                #pragma unroll
                for (int j = 0; j < INNER; ++j) isum[j] = 0.f;
                {
                    int nm1 = n - 1;
                    int k1 = nm1 < 1 ? nm1 : 1;
                    int k2 = nm1 < 2 ? nm1 : 2;
                    int k3 = nm1 < 3 ? nm1 : 3;
                    int c0 = adjc[rp0];
                    int c1 = adjc[rp0 + k1];
                    int c2 = adjc[rp0 + k2];
                    int c3 = adjc[rp0 + k3];
                    float f1 = n > 1 ? 1.f : 0.f;
                    float f2 = n > 2 ? 1.f : 0.f;
                    float f3 = n > 3 ? 1.f : 0.f;
                    const float4* p0 = (const float4*)(msg_s + (size_t)c0 * REC);
                    const float4* p1 = (const float4*)(msg_s + (size_t)c1 * REC);
                    const float4* p2 = (const float4*)(msg_s + (size_t)c2 * REC);
                    const float4* p3 = (const float4*)(msg_s + (size_t)c3 * REC);
                    #pragma unroll
                    for (int q = 0; q < 5; ++q) {
                        float4 v0 = p0[q], v1 = p1[q], v2 = p2[q], v3 = p3[q];
                        isum[4*q]   += v0.x + f1 * v1.x + f2 * v2.x + f3 * v3.x;
                        isum[4*q+1] += v0.y + f1 * v1.y + f2 * v2.y + f3 * v3.y;
                        isum[4*q+2] += v0.z + f1 * v1.z + f2 * v2.z + f3 * v3.z;
                        isum[4*q+3] += v0.w + f1 * v1.w + f2 * v2.w + f3 * v3.w;
                    }
                    for (int r = rp0 + 4; r < rp1; ++r) {
                        int c = adjc[r];
                        const float4* mp = (const float4*)(msg_s + (size_t)c * REC);
                        #pragma unroll
                        for (int q = 0; q < 5; ++q) {
                            float4 v = mp[q];
                            isum[4*q]   += v.x; isum[4*q+1] += v.y;
                            isum[4*q+2] += v.z; isum[4*q+3] += v.w;
                        }
                    }
                }
                float hid[HID];
                #pragma unroll
                for (int j = 0; j < HID; ++j) hid[j] = nb1[j];
                for (int k = 0; k < ATOM; ++k) {
                    float xk = a[k];
                    #pragma unroll
                    for (int j = 0; j < HID; ++j) hid[j] += xk * nw1[k * HID + j];
                }
                for (int k = 0; k < INNER; ++k) {
                    float xk = isum[k];
                    #pragma unroll
                    for (int j = 0; j < HID; ++j) hid[j] += xk * nw1[(ATOM + k) * HID + j];
                }
                #pragma unroll
                for (int j = 0; j < HID; ++j) hid[j] = leaky(hid[j]);
                #pragma unroll
                for (int j = 0; j < REC; ++j) o[j] = nb2[j];
                for (int k = 0; k < HID; ++k) {
                    float hk = hid[k];
                    #pragma unroll
                    for (int j = 0; j < REC; ++j) o[j] += hk * nw2[k * REC + j];
                }
            }
            #pragma unroll
            for (int j = 0; j < REC; ++j) o[j] = leaky(o[j]);
            // ---- emit ----
            if (gr >= 0) {
                float* gp = g + (size_t)gr * REC;
                #pragma unroll
                for (int j = 0; j < REC; ++j) atomicAdd(&gp[j], o[j]);
            }
            if (pp >= 0) {
                float b0 = bond_s[(size_t)pos * BOND + 0];
                float b1 = bond_s[(size_t)pos * BOND + 1];
                float b2 = bond_s[(size_t)pos * BOND + 2];
                float m[INNER];
                #pragma unroll
                for (int j = 0; j < INNER; ++j)
                    m[j] = ib[j] + b0 * iw[0 * INNER + j] + b1 * iw[1 * INNER + j]
                                 + b2 * iw[2 * INNER + j];
                #pragma unroll
                for (int k = 0; k < REC; ++k) {
                    float ok = o[k];
                    #pragma unroll
                    for (int j = 0; j < INNER; ++j) m[j] += ok * iw[(BOND + k) * INNER + j];
                }
                float4* mp = (float4*)(msg_s + (size_t)pos * REC);
                #pragma unroll
                for (int j = 0; j < 5; ++j)
                    mp[j] = make_float4(leaky(m[4*j]), leaky(m[4*j+1]),
                                        leaky(m[4*j+2]), leaky(m[4*j+3]));
            }
        }
        gbar(bar, NB * ++ep);
    }

    // ---- P22: graph readout ----
    for (int tg = tid; tg < NG; tg += GT) {
        const float* gv = g + (size_t)tg * REC;
        float gl[REC];
        #pragma unroll
        for (int k = 0; k < REC; ++k) gl[k] = gv[k];
        float acc = ob2[0];
        for (int j = 0; j < OHID; ++j) {
            float s = ob1[j];
            #pragma unroll
            for (int k = 0; k < REC; ++k) s += gl[k] * ow1[k * OHID + j];
            acc += tanhf(s) * ow2[j];
        }
        out[tg] = acc;
    }
}

extern "C" void kernel_launch(void* const* d_in, const int* in_sizes, int n_in,
                              void* d_out, int out_size, void* d_ws, size_t ws_size,
                              hipStream_t stream) {
    const float* atom    = (const float*)d_in[0];
    const float* bond    = (const float*)d_in[1];
    const int*   parent  = (const int*)d_in[2];
    const int*   child   = (const int*)d_in[3];
    const int*   depth   = (const int*)d_in[4];
    const int*   gid     = (const int*)d_in[5];
    const float* isr     = (const float*)d_in[6];
    const float* inner_w = (const float*)d_in[7];
    const float* inner_b = (const float*)d_in[8];
    const float* net_w1  = (const float*)d_in[9];
    const float* net_b1  = (const float*)d_in[10];
    const float* net_w2  = (const float*)d_in[11];
    const float* net_b2  = (const float*)d_in[12];
    const float* net0_w1 = (const float*)d_in[13];
    const float* net0_b1 = (const float*)d_in[14];
    const float* net0_w2 = (const float*)d_in[15];
    const float* net0_b2 = (const float*)d_in[16];
    const float* out_w1  = (const float*)d_in[17];
    const float* out_b1  = (const float*)d_in[18];
    const float* out_w2  = (const float*)d_in[19];
    const float* out_b2  = (const float*)d_in[20];
    float* out = (float*)d_out;

    char* ws = (char*)d_ws;
    size_t o = 0;
    float* msg_s    = (float*)(ws + o);  o += (size_t)NN * REC * 4;    // 83.9 MB
    float* g        = (float*)(ws + o);  o += (size_t)NG * REC * 4;    // 1.3 MB
    float* bond_s   = (float*)(ws + o);  o += (size_t)NN * BOND * 4;   // 12.6 MB
    int* node_list  = (int*)(ws + o);    o += (size_t)NN * 4;          // 4.2 MB
    int* inv        = (int*)(ws + o);    o += (size_t)NN * 4;          // 4.2 MB (reused as rank)
    int* pp_s       = (int*)(ws + o);    o += (size_t)NN * 4;          // 4.2 MB
    int* groot_s    = (int*)(ws + o);    o += (size_t)NN * 4;          // 4.2 MB
    int* row_ptr    = (int*)(ws + o);    o += (size_t)(NN + 4) * 4;    // 4.2 MB
    int* cnt_i      = (int*)(ws + o);    o += (size_t)NN * 4;          // 4.2 MB
    int* adjc       = (int*)(ws + o);    o += (size_t)NE * 4;          // 3.9 MB
    int* bsum       = (int*)(ws + o);    o += NB * 4;
    int* boff       = (int*)(ws + o);    o += (NB + 1) * 4 + 12;
    int* cnt16      = (int*)(ws + o);    o += NBIN * 16 * 4;           // padded: 1 bin / line
    int* off        = (int*)(ws + o);    o += (NBIN + 1) * 4 + 12;
    int* cur        = (int*)(ws + o);    o += NBIN * 16 * 4;           // padded
    int* bar        = (int*)(ws + o);    o += 256;
    // total ~127 MB

    k_zero_bar<<<1, 64, 0, stream>>>(bar);
    k_fused<<<NB, NT, 0, stream>>>(atom, bond, parent, child, depth, gid, isr,
                                   inner_w, inner_b, net_w1, net_b1, net_w2, net_b2,
                                   net0_w1, net0_b1, net0_w2, net0_b2,
                                   out_w1, out_b1, out_w2, out_b2, out,
                                   msg_s, g, bond_s, node_list, inv, pp_s, groot_s,
                                   row_ptr, cnt_i, adjc, bsum, boff,
                                   cnt16, off, cur, bar);
}

// Round 8
// 3100.259 us; speedup vs baseline: 1.0279x; 1.0279x over previous
//
#include <hip/hip_runtime.h>

#define ATOM  14
#define BOND  3
#define INNER 20
#define HID   34
#define REC   20
#define OHID  25
#define NN    1048576
#define NE    983040
#define NG    16384
#define NBIN  16

#define NB    1024
#define NT    256
#define GT    (NB*NT)        // 262144
#define CHUNK (NN/NB)        // 1024 positions per block for row scan
#define SE    (CHUNK/NT)     // 4
#define SB    (NB/NT)        // 4 block-sums per thread in scanB

__device__ __forceinline__ float leaky(float x) { return x >= 0.f ? x : 0.01f * x; }

// grid-wide barrier: device-scope counter + fences (cross-XCD safe).
// s_sleep(32) poll (~850 ns) keeps 1024 spinners from saturating the fabric.
__device__ __forceinline__ void gbar(int* bar, int goal) {
    __syncthreads();
    if (threadIdx.x == 0) {
        __threadfence();   // release
        __hip_atomic_fetch_add(bar, 1, __ATOMIC_RELEASE, __HIP_MEMORY_SCOPE_AGENT);
        while (__hip_atomic_load(bar, __ATOMIC_RELAXED, __HIP_MEMORY_SCOPE_AGENT) < goal)
            __builtin_amdgcn_s_sleep(32);
        __threadfence();   // acquire
    }
    __syncthreads();
}

__global__ void k_zero_bar(int* bar) {
    if (threadIdx.x == 0 && blockIdx.x == 0) *bar = 0;
}

__global__ __launch_bounds__(NT, 4) void k_fused(
    const float* __restrict__ atom, const float* __restrict__ bond,
    const int* __restrict__ parent, const int* __restrict__ child,
    const int* __restrict__ depth, const int* __restrict__ gid,
    const float* __restrict__ isr,
    const float* __restrict__ iw, const float* __restrict__ ib,
    const float* __restrict__ nw1, const float* __restrict__ nb1,
    const float* __restrict__ nw2, const float* __restrict__ nb2,
    const float* __restrict__ l0w1, const float* __restrict__ l0b1,
    const float* __restrict__ l0w2, const float* __restrict__ l0b2,
    const float* __restrict__ ow1, const float* __restrict__ ob1,
    const float* __restrict__ ow2, const float* __restrict__ ob2,
    float* __restrict__ out,
    float* msg_s, float* g, float* bond_s,
    int* node_list, int* inv, int* pp_s, int* groot_s,
    int* row_ptr, int* cnt_i, int* adjc, int* ccnt_s,
    int* bsum, int* boff, int* cnt16, int* cur, int* bar)
{
    __shared__ int sh[NT];
    __shared__ int soff[NBIN + 1];   // bin offsets, persists across all phases
    __shared__ int lh[NBIN];
    __shared__ int lbase[NBIN];
    const int t = threadIdx.x;
    const int tid = blockIdx.x * NT + t;
    int ep = 0;

    // ---- P0: init ----
    for (int i = tid; i < NN; i += GT) { cnt_i[i] = 0; pp_s[i] = -1; }
    for (int i = tid; i < NG * REC; i += GT) g[i] = 0.f;
    if (tid < NBIN) { cnt16[tid << 4] = 0; cur[tid << 4] = 0; }
    gbar(bar, NB * ++ep);

    // ---- P1: child-count atomics + depth histogram ----
    if (t < NBIN) lh[t] = 0;
    __syncthreads();
    for (int e = tid; e < NE; e += GT) atomicAdd(&cnt_i[parent[e]], 1);
    for (int i = tid; i < NN; i += GT) atomicAdd(&lh[depth[i]], 1);
    __syncthreads();
    if (t < NBIN && lh[t]) atomicAdd(&cnt16[t << 4], lh[t]);
    gbar(bar, NB * ++ep);

    // ---- P2: counting sort by depth (per-block redundant bin scan -> soff in LDS) ----
    if (t == 0) {
        int s = 0;
        for (int d = 0; d < NBIN; ++d) { soff[d] = s; s += cnt16[d << 4]; }
        soff[NBIN] = s;
    }
    __syncthreads();
    for (int chunk = blockIdx.x; chunk < NN / NT; chunk += NB) {
        __syncthreads();
        if (t < NBIN) lh[t] = 0;
        __syncthreads();
        int i = chunk * NT + t;
        int b = depth[i];
        int r = atomicAdd(&lh[b], 1);
        __syncthreads();
        if (t < NBIN && lh[t]) lbase[t] = atomicAdd(&cur[t << 4], lh[t]) + soff[t];
        __syncthreads();
        int pos = lbase[b] + r;
        node_list[pos] = i;
        inv[i] = pos;
        groot_s[pos] = (isr[i] != 0.f) ? gid[i] : -1;
    }
    gbar(bar, NB * ++ep);

    // ---- P3: edge prep + per-chunk exclusive scan of child counts (also save ccnt_s) ----
    for (int e = tid; e < NE; e += GT) {
        int cpos = inv[child[e]];
        pp_s[cpos] = inv[parent[e]];
        bond_s[(size_t)cpos * BOND + 0] = bond[(size_t)e * BOND + 0];
        bond_s[(size_t)cpos * BOND + 1] = bond[(size_t)e * BOND + 1];
        bond_s[(size_t)cpos * BOND + 2] = bond[(size_t)e * BOND + 2];
    }
    {
        int base0 = blockIdx.x * CHUNK + t * SE;
        int v[SE]; int sum = 0;
        #pragma unroll
        for (int k = 0; k < SE; ++k) { v[k] = cnt_i[node_list[base0 + k]]; sum += v[k]; }
        #pragma unroll
        for (int k = 0; k < SE; ++k) ccnt_s[base0 + k] = v[k];
        __syncthreads();
        sh[t] = sum;
        __syncthreads();
        for (int ofs = 1; ofs < NT; ofs <<= 1) {
            int x = (t >= ofs) ? sh[t - ofs] : 0;
            __syncthreads();
            sh[t] += x;
            __syncthreads();
        }
        int run = sh[t] - sum;
        #pragma unroll
        for (int k = 0; k < SE; ++k) { row_ptr[base0 + k] = run; run += v[k]; }
        if (t == NT - 1) bsum[blockIdx.x] = sh[t];
    }
    gbar(bar, NB * ++ep);

    // ---- P4: block0 scans block sums; all blocks zero rank counters (reuse inv) ----
    if (blockIdx.x == 0) {
        int v[SB]; int p = 0;
        #pragma unroll
        for (int k = 0; k < SB; ++k) { v[k] = bsum[t * SB + k]; p += v[k]; }
        sh[t] = p;
        __syncthreads();
        for (int ofs = 1; ofs < NT; ofs <<= 1) {
            int x = (t >= ofs) ? sh[t - ofs] : 0;
            __syncthreads();
            sh[t] += x;
            __syncthreads();
        }
        int run = sh[t] - p;
        #pragma unroll
        for (int k = 0; k < SB; ++k) { boff[t * SB + k] = run; run += v[k]; }
    }
    for (int i = tid; i < NN; i += GT) inv[i] = 0;
    gbar(bar, NB * ++ep);

    // ---- P5: CSR child lists ----
    for (int pos = tid; pos < NN; pos += GT) {
        int pp = pp_s[pos];
        if (pp >= 0) {
            int r = atomicAdd(&inv[pp], 1);
            adjc[row_ptr[pp] + boff[pp >> 10] + r] = pos;
        }
    }
    gbar(bar, NB * ++ep);

    // ---- P6..P21: levels d = 15..0 (leaf via net0, internal via gather+net) ----
    for (int d = NBIN - 1; d >= 0; --d) {
        int q0 = soff[d], q1 = soff[d + 1];
        for (int pos = q0 + tid; pos < q1; pos += GT) {
            // independent loads first
            int n  = ccnt_s[pos];
            int i  = node_list[pos];
            int pp = pp_s[pos];
            int gr = groot_s[pos];
            const float2* a2 = (const float2*)(atom + (size_t)i * ATOM);
            float a[ATOM];
            #pragma unroll
            for (int k = 0; k < 7; ++k) { float2 v = a2[k]; a[2*k] = v.x; a[2*k+1] = v.y; }
            float o[REC];
            if (n == 0) {
                // ---- leaf: net0 MLP ----
                float hid[HID];
                #pragma unroll
                for (int j = 0; j < HID; ++j) hid[j] = l0b1[j];
                for (int k = 0; k < ATOM; ++k) {
                    float ak = a[k];
                    #pragma unroll
                    for (int j = 0; j < HID; ++j) hid[j] += ak * l0w1[k * HID + j];
                }
                #pragma unroll
                for (int j = 0; j < HID; ++j) hid[j] = leaky(hid[j]);
                #pragma unroll
                for (int j = 0; j < REC; ++j) o[j] = l0b2[j];
                for (int k = 0; k < HID; ++k) {
                    float hk = hid[k];
                    #pragma unroll
                    for (int j = 0; j < REC; ++j) o[j] += hk * l0w2[k * REC + j];
                }
            } else {
                // ---- internal: gather children msgs (4-wide clamped), net MLP ----
                int rp0 = row_ptr[pos] + boff[pos >> 10];
                int rp1 = rp0 + n;
                float isum[INNER];
                #pragma unroll
                for (int j = 0; j < INNER; ++j) isum[j] = 0.f;
                {
                    int nm1 = n - 1;
                    int k1 = nm1 < 1 ? nm1 : 1;
                    int k2 = nm1 < 2 ? nm1 : 2;
                    int k3 = nm1 < 3 ? nm1 : 3;
                    int c0 = adjc[rp0];
                    int c1 = adjc[rp0 + k1];
                    int c2 = adjc[rp0 + k2];
                    int c3 = adjc[rp0 + k3];
                    float f1 = n > 1 ? 1.f : 0.f;
                    float f2 = n > 2 ? 1.f : 0.f;
                    float f3 = n > 3 ? 1.f : 0.f;
                    const float4* p0 = (const float4*)(msg_s + (size_t)c0 * REC);
                    const float4* p1 = (const float4*)(msg_s + (size_t)c1 * REC);
                    const float4* p2 = (const float4*)(msg_s + (size_t)c2 * REC);
                    const float4* p3 = (const float4*)(msg_s + (size_t)c3 * REC);
                    #pragma unroll
                    for (int q = 0; q < 5; ++q) {
                        float4 v0 = p0[q], v1 = p1[q], v2 = p2[q], v3 = p3[q];
                        isum[4*q]   += v0.x + f1 * v1.x + f2 * v2.x + f3 * v3.x;
                        isum[4*q+1] += v0.y + f1 * v1.y + f2 * v2.y + f3 * v3.y;
                        isum[4*q+2] += v0.z + f1 * v1.z + f2 * v2.z + f3 * v3.z;
                        isum[4*q+3] += v0.w + f1 * v1.w + f2 * v2.w + f3 * v3.w;
                    }
                    for (int r = rp0 + 4; r < rp1; ++r) {
                        int c = adjc[r];
                        const float4* mp = (const float4*)(msg_s + (size_t)c * REC);
                        #pragma unroll
                        for (int q = 0; q < 5; ++q) {
                            float4 v = mp[q];
                            isum[4*q]   += v.x; isum[4*q+1] += v.y;
                            isum[4*q+2] += v.z; isum[4*q+3] += v.w;
                        }
                    }
                }
                float hid[HID];
                #pragma unroll
                for (int j = 0; j < HID; ++j) hid[j] = nb1[j];
                for (int k = 0; k < ATOM; ++k) {
                    float xk = a[k];
                    #pragma unroll
                    for (int j = 0; j < HID; ++j) hid[j] += xk * nw1[k * HID + j];
                }
                for (int k = 0; k < INNER; ++k) {
                    float xk = isum[k];
                    #pragma unroll
                    for (int j = 0; j < HID; ++j) hid[j] += xk * nw1[(ATOM + k) * HID + j];
                }
                #pragma unroll
                for (int j = 0; j < HID; ++j) hid[j] = leaky(hid[j]);
                #pragma unroll
                for (int j = 0; j < REC; ++j) o[j] = nb2[j];
                for (int k = 0; k < HID; ++k) {
                    float hk = hid[k];
                    #pragma unroll
                    for (int j = 0; j < REC; ++j) o[j] += hk * nw2[k * REC + j];
                }
            }
            #pragma unroll
            for (int j = 0; j < REC; ++j) o[j] = leaky(o[j]);
            // ---- emit ----
            if (gr >= 0) {
                float* gp = g + (size_t)gr * REC;
                #pragma unroll
                for (int j = 0; j < REC; ++j) atomicAdd(&gp[j], o[j]);
            }
            if (pp >= 0) {
                float b0 = bond_s[(size_t)pos * BOND + 0];
                float b1 = bond_s[(size_t)pos * BOND + 1];
                float b2 = bond_s[(size_t)pos * BOND + 2];
                float m[INNER];
                #pragma unroll
                for (int j = 0; j < INNER; ++j)
                    m[j] = ib[j] + b0 * iw[0 * INNER + j] + b1 * iw[1 * INNER + j]
                                 + b2 * iw[2 * INNER + j];
                #pragma unroll
                for (int k = 0; k < REC; ++k) {
                    float ok = o[k];
                    #pragma unroll
                    for (int j = 0; j < INNER; ++j) m[j] += ok * iw[(BOND + k) * INNER + j];
                }
                float4* mp = (float4*)(msg_s + (size_t)pos * REC);
                #pragma unroll
                for (int j = 0; j < 5; ++j)
                    mp[j] = make_float4(leaky(m[4*j]), leaky(m[4*j+1]),
                                        leaky(m[4*j+2]), leaky(m[4*j+3]));
            }
        }
        gbar(bar, NB * ++ep);
    }

    // ---- P22: graph readout ----
    for (int tg = tid; tg < NG; tg += GT) {
        const float* gv = g + (size_t)tg * REC;
        float gl[REC];
        #pragma unroll
        for (int k = 0; k < REC; ++k) gl[k] = gv[k];
        float acc = ob2[0];
        for (int j = 0; j < OHID; ++j) {
            float s = ob1[j];
            #pragma unroll
            for (int k = 0; k < REC; ++k) s += gl[k] * ow1[k * OHID + j];
            acc += tanhf(s) * ow2[j];
        }
        out[tg] = acc;
    }
}

extern "C" void kernel_launch(void* const* d_in, const int* in_sizes, int n_in,
                              void* d_out, int out_size, void* d_ws, size_t ws_size,
                              hipStream_t stream) {
    const float* atom    = (const float*)d_in[0];
    const float* bond    = (const float*)d_in[1];
    const int*   parent  = (const int*)d_in[2];
    const int*   child   = (const int*)d_in[3];
    const int*   depth   = (const int*)d_in[4];
    const int*   gid     = (const int*)d_in[5];
    const float* isr     = (const float*)d_in[6];
    const float* inner_w = (const float*)d_in[7];
    const float* inner_b = (const float*)d_in[8];
    const float* net_w1  = (const float*)d_in[9];
    const float* net_b1  = (const float*)d_in[10];
    const float* net_w2  = (const float*)d_in[11];
    const float* net_b2  = (const float*)d_in[12];
    const float* net0_w1 = (const float*)d_in[13];
    const float* net0_b1 = (const float*)d_in[14];
    const float* net0_w2 = (const float*)d_in[15];
    const float* net0_b2 = (const float*)d_in[16];
    const float* out_w1  = (const float*)d_in[17];
    const float* out_b1  = (const float*)d_in[18];
    const float* out_w2  = (const float*)d_in[19];
    const float* out_b2  = (const float*)d_in[20];
    float* out = (float*)d_out;

    char* ws = (char*)d_ws;
    size_t o = 0;
    float* msg_s    = (float*)(ws + o);  o += (size_t)NN * REC * 4;    // 83.9 MB
    float* g        = (float*)(ws + o);  o += (size_t)NG * REC * 4;    // 1.3 MB
    float* bond_s   = (float*)(ws + o);  o += (size_t)NN * BOND * 4;   // 12.6 MB
    int* node_list  = (int*)(ws + o);    o += (size_t)NN * 4;          // 4.2 MB
    int* inv        = (int*)(ws + o);    o += (size_t)NN * 4;          // 4.2 MB (reused as rank)
    int* pp_s       = (int*)(ws + o);    o += (size_t)NN * 4;          // 4.2 MB
    int* groot_s    = (int*)(ws + o);    o += (size_t)NN * 4;          // 4.2 MB
    int* row_ptr    = (int*)(ws + o);    o += (size_t)(NN + 4) * 4;    // 4.2 MB
    int* cnt_i      = (int*)(ws + o);    o += (size_t)NN * 4;          // 4.2 MB
    int* adjc       = (int*)(ws + o);    o += (size_t)NE * 4;          // 3.9 MB
    int* ccnt_s     = (int*)(ws + o);    o += (size_t)NN * 4;          // 4.2 MB
    int* bsum       = (int*)(ws + o);    o += NB * 4;
    int* boff       = (int*)(ws + o);    o += (NB + 1) * 4 + 12;
    int* cnt16      = (int*)(ws + o);    o += NBIN * 16 * 4;           // padded: 1 bin / line
    int* cur        = (int*)(ws + o);    o += NBIN * 16 * 4;           // padded
    int* bar        = (int*)(ws + o);    o += 256;
    // total ~132 MB

    k_zero_bar<<<1, 64, 0, stream>>>(bar);
    k_fused<<<NB, NT, 0, stream>>>(atom, bond, parent, child, depth, gid, isr,
                                   inner_w, inner_b, net_w1, net_b1, net_w2, net_b2,
                                   net0_w1, net0_b1, net0_w2, net0_b2,
                                   out_w1, out_b1, out_w2, out_b2, out,
                                   msg_s, g, bond_s, node_list, inv, pp_s, groot_s,
                                   row_ptr, cnt_i, adjc, ccnt_s, bsum, boff,
                                   cnt16, cur, bar);
}

// Round 9
// 2348.486 us; speedup vs baseline: 1.3570x; 1.3201x over previous
//
#include <hip/hip_runtime.h>

#define ATOM  14
#define BOND  3
#define INNER 20
#define HID   34
#define REC   20
#define OHID  25
#define NN    1048576
#define NE    983040
#define NG    16384
#define NBIN  32

#define NB    512
#define NT    256
#define GT    (NB*NT)        // 131072
#define SPAN  (NN/NB)        // 2048 positions per block
#define SE    (SPAN/NT)      // 8

__device__ __forceinline__ float leaky(float x) { return x >= 0.f ? x : 0.01f * x; }

// grid-wide barrier: device-scope counter + fences (cross-XCD safe)
__device__ __forceinline__ void gbar(int* bar, int goal) {
    __syncthreads();
    if (threadIdx.x == 0) {
        __threadfence();   // release
        __hip_atomic_fetch_add(bar, 1, __ATOMIC_RELEASE, __HIP_MEMORY_SCOPE_AGENT);
        while (__hip_atomic_load(bar, __ATOMIC_RELAXED, __HIP_MEMORY_SCOPE_AGENT) < goal)
            __builtin_amdgcn_s_sleep(32);
        __threadfence();   // acquire
    }
    __syncthreads();
}

// zero hc/cnt16/adj_total/bar before the big kernel
__global__ void k_pre(int* hc_i, int* cnt16, int* adj_total, int* bar) {
    int i = blockIdx.x * 256 + threadIdx.x;   // 65536 threads
    #pragma unroll
    for (int k = 0; k < (NN / 4) / 65536; ++k) hc_i[i + k * 65536] = 0;
    if (i < NBIN) cnt16[i << 4] = 0;
    if (i == NBIN) { *adj_total = 0; }
    if (i == NBIN + 1) { *bar = 0; }
}

__global__ __launch_bounds__(NT) void k_fused(
    const float* __restrict__ atom, const float* __restrict__ bond,
    const int* __restrict__ parent, const int* __restrict__ child,
    const int* __restrict__ depth, const int* __restrict__ gid,
    const float* __restrict__ isr,
    const float* __restrict__ iw, const float* __restrict__ ib,
    const float* __restrict__ nw1, const float* __restrict__ nb1,
    const float* __restrict__ nw2, const float* __restrict__ nb2,
    const float* __restrict__ l0w1, const float* __restrict__ l0b1,
    const float* __restrict__ l0w2, const float* __restrict__ l0b2,
    const float* __restrict__ ow1, const float* __restrict__ ob1,
    const float* __restrict__ ow2, const float* __restrict__ ob2,
    float* __restrict__ out,
    float* msg_s, float* g, float* bond_s,
    int* node_list, int* inv, int* pp_s, int* rank_s, int* groot_s,
    int* row_ptr, int* cnt_pos, int* adjc,
    unsigned char* hc, int* blkbase, int* cnt16, int* adj_total, int* bar)
{
    __shared__ int sh[NT];
    __shared__ int soff[NBIN + 1];   // persists through all phases
    __shared__ int lh[NBIN];
    __shared__ int lbase[NBIN];
    __shared__ int sbase;
    const int t = threadIdx.x;
    const int tid = blockIdx.x * NT + t;
    const int span0 = blockIdx.x * SPAN;
    int ep = 0;

    // ---- P0a: hc marks + zero cnt_pos/pp_s/g ----
    for (int e = tid; e < NE; e += GT) hc[parent[e]] = 1;   // racy same-value: fine
    for (int i = tid; i < NN; i += GT) { cnt_pos[i] = 0; pp_s[i] = -1; }
    for (int i = tid; i < NG * REC; i += GT) g[i] = 0.f;
    gbar(bar, NB * ++ep);

    // ---- P0b: per-block 32-bin histogram of own span; global base via 1 atomic/bin ----
    if (t < NBIN) lh[t] = 0;
    __syncthreads();
    for (int i = span0 + t; i < span0 + SPAN; i += NT) {
        int d = depth[i];
        int b = (hc[i] && d < 15) ? d : 16 + d;
        atomicAdd(&lh[b], 1);
    }
    __syncthreads();
    if (t < NBIN) blkbase[blockIdx.x * NBIN + t] = atomicAdd(&cnt16[t << 4], lh[t]);
    gbar(bar, NB * ++ep);

    // ---- P1: scatter (sort) own span; soff scan kept in LDS ----
    if (t == 0) {
        int s = 0;
        for (int b = 0; b < NBIN; ++b) { soff[b] = s; s += cnt16[b << 4]; }
        soff[NBIN] = s;
    }
    if (t < NBIN) { lbase[t] = blkbase[blockIdx.x * NBIN + t]; lh[t] = 0; }
    __syncthreads();
    for (int i = span0 + t; i < span0 + SPAN; i += NT) {
        int d = depth[i];
        int b = (hc[i] && d < 15) ? d : 16 + d;
        int r = atomicAdd(&lh[b], 1);            // LDS rank within block
        int pos = soff[b] + lbase[b] + r;
        node_list[pos] = i;
        inv[i] = pos;
        groot_s[pos] = (isr[i] != 0.f) ? gid[i] : -1;
    }
    gbar(bar, NB * ++ep);

    // ---- P2: edge pass — THE scattered-atomic pass (rank == count) ----
    for (int e = tid; e < NE; e += GT) {
        int cpos = inv[child[e]];
        int pp   = inv[parent[e]];
        int r = atomicAdd(&cnt_pos[pp], 1);
        pp_s[cpos] = pp;
        rank_s[cpos] = r;
        bond_s[(size_t)cpos * BOND + 0] = bond[(size_t)e * BOND + 0];
        bond_s[(size_t)cpos * BOND + 1] = bond[(size_t)e * BOND + 1];
        bond_s[(size_t)cpos * BOND + 2] = bond[(size_t)e * BOND + 2];
    }
    gbar(bar, NB * ++ep);

    // ---- P3: row_ptr = span prefix + one block-base atomic (orderless CSR) ----
    {
        int base0 = span0 + t * SE;
        int v[SE]; int sum = 0;
        #pragma unroll
        for (int k = 0; k < SE; ++k) { v[k] = cnt_pos[base0 + k]; sum += v[k]; }
        sh[t] = sum;
        __syncthreads();
        for (int ofs = 1; ofs < NT; ofs <<= 1) {
            int x = (t >= ofs) ? sh[t - ofs] : 0;
            __syncthreads();
            sh[t] += x;
            __syncthreads();
        }
        if (t == NT - 1) sbase = atomicAdd(adj_total, sh[t]);
        __syncthreads();
        int run = sbase + sh[t] - sum;
        #pragma unroll
        for (int k = 0; k < SE; ++k) { row_ptr[base0 + k] = run; run += v[k]; }
    }
    gbar(bar, NB * ++ep);

    // ---- P4: adjc fill (no atomics) ----
    for (int pos = tid; pos < NN; pos += GT) {
        int pp = pp_s[pos];
        if (pp >= 0) adjc[row_ptr[pp] + rank_s[pos]] = pos;
    }
    gbar(bar, NB * ++ep);

    // ---- P5: leaf phase (bins 16..31), uniform waves ----
    for (int pos = soff[16] + tid; pos < NN; pos += GT) {
        int i = node_list[pos];
        int pp = pp_s[pos];
        int gr = groot_s[pos];
        const float2* a2 = (const float2*)(atom + (size_t)i * ATOM);
        float a[ATOM];
        #pragma unroll
        for (int k = 0; k < 7; ++k) { float2 v = a2[k]; a[2*k] = v.x; a[2*k+1] = v.y; }
        float hid[HID];
        #pragma unroll
        for (int j = 0; j < HID; ++j) hid[j] = l0b1[j];
        for (int k = 0; k < ATOM; ++k) {
            float ak = a[k];
            #pragma unroll
            for (int j = 0; j < HID; ++j) hid[j] += ak * l0w1[k * HID + j];
        }
        #pragma unroll
        for (int j = 0; j < HID; ++j) hid[j] = leaky(hid[j]);
        float o[REC];
        #pragma unroll
        for (int j = 0; j < REC; ++j) o[j] = l0b2[j];
        for (int k = 0; k < HID; ++k) {
            float hk = hid[k];
            #pragma unroll
            for (int j = 0; j < REC; ++j) o[j] += hk * l0w2[k * REC + j];
        }
        #pragma unroll
        for (int j = 0; j < REC; ++j) o[j] = leaky(o[j]);
        if (gr >= 0) {
            float* gp = g + (size_t)gr * REC;
            #pragma unroll
            for (int j = 0; j < REC; ++j) atomicAdd(&gp[j], o[j]);
        }
        if (pp >= 0) {
            float b0 = bond_s[(size_t)pos * BOND + 0];
            float b1 = bond_s[(size_t)pos * BOND + 1];
            float b2 = bond_s[(size_t)pos * BOND + 2];
            float m[INNER];
            #pragma unroll
            for (int j = 0; j < INNER; ++j)
                m[j] = ib[j] + b0 * iw[0 * INNER + j] + b1 * iw[1 * INNER + j]
                             + b2 * iw[2 * INNER + j];
            #pragma unroll
            for (int k = 0; k < REC; ++k) {
                float ok = o[k];
                #pragma unroll
                for (int j = 0; j < INNER; ++j) m[j] += ok * iw[(BOND + k) * INNER + j];
            }
            float4* mp = (float4*)(msg_s + (size_t)pos * REC);
            #pragma unroll
            for (int j = 0; j < 5; ++j)
                mp[j] = make_float4(leaky(m[4*j]), leaky(m[4*j+1]),
                                    leaky(m[4*j+2]), leaky(m[4*j+3]));
        }
    }
    gbar(bar, NB * ++ep);

    // ---- P6..P20: internal levels d = 14..0, uniform waves ----
    for (int d = 14; d >= 0; --d) {
        int q0 = soff[d], q1 = soff[d + 1];
        for (int pos = q0 + tid; pos < q1; pos += GT) {
            int n  = cnt_pos[pos];
            int i  = node_list[pos];
            int pp = pp_s[pos];
            int gr = groot_s[pos];
            int rp0 = row_ptr[pos];
            const float2* a2 = (const float2*)(atom + (size_t)i * ATOM);
            float a[ATOM];
            #pragma unroll
            for (int k = 0; k < 7; ++k) { float2 v = a2[k]; a[2*k] = v.x; a[2*k+1] = v.y; }
            float isum[INNER];
            #pragma unroll
            for (int j = 0; j < INNER; ++j) isum[j] = 0.f;
            {
                int rp1 = rp0 + n;
                int nm1 = n - 1;
                int k1 = nm1 < 1 ? nm1 : 1;
                int k2 = nm1 < 2 ? nm1 : 2;
                int k3 = nm1 < 3 ? nm1 : 3;
                int c0 = adjc[rp0];
                int c1 = adjc[rp0 + k1];
                int c2 = adjc[rp0 + k2];
                int c3 = adjc[rp0 + k3];
                float f1 = n > 1 ? 1.f : 0.f;
                float f2 = n > 2 ? 1.f : 0.f;
                float f3 = n > 3 ? 1.f : 0.f;
                const float4* p0 = (const float4*)(msg_s + (size_t)c0 * REC);
                const float4* p1 = (const float4*)(msg_s + (size_t)c1 * REC);
                const float4* p2 = (const float4*)(msg_s + (size_t)c2 * REC);
                const float4* p3 = (const float4*)(msg_s + (size_t)c3 * REC);
                #pragma unroll
                for (int q = 0; q < 5; ++q) {
                    float4 v0 = p0[q], v1 = p1[q], v2 = p2[q], v3 = p3[q];
                    isum[4*q]   += v0.x + f1 * v1.x + f2 * v2.x + f3 * v3.x;
                    isum[4*q+1] += v0.y + f1 * v1.y + f2 * v2.y + f3 * v3.y;
                    isum[4*q+2] += v0.z + f1 * v1.z + f2 * v2.z + f3 * v3.z;
                    isum[4*q+3] += v0.w + f1 * v1.w + f2 * v2.w + f3 * v3.w;
                }
                for (int r = rp0 + 4; r < rp1; ++r) {
                    int c = adjc[r];
                    const float4* mp = (const float4*)(msg_s + (size_t)c * REC);
                    #pragma unroll
                    for (int q = 0; q < 5; ++q) {
                        float4 v = mp[q];
                        isum[4*q]   += v.x; isum[4*q+1] += v.y;
                        isum[4*q+2] += v.z; isum[4*q+3] += v.w;
                    }
                }
            }
            float hid[HID];
            #pragma unroll
            for (int j = 0; j < HID; ++j) hid[j] = nb1[j];
            for (int k = 0; k < ATOM; ++k) {
                float xk = a[k];
                #pragma unroll
                for (int j = 0; j < HID; ++j) hid[j] += xk * nw1[k * HID + j];
            }
            for (int k = 0; k < INNER; ++k) {
                float xk = isum[k];
                #pragma unroll
                for (int j = 0; j < HID; ++j) hid[j] += xk * nw1[(ATOM + k) * HID + j];
            }
            #pragma unroll
            for (int j = 0; j < HID; ++j) hid[j] = leaky(hid[j]);
            float o[REC];
            #pragma unroll
            for (int j = 0; j < REC; ++j) o[j] = nb2[j];
            for (int k = 0; k < HID; ++k) {
                float hk = hid[k];
                #pragma unroll
                for (int j = 0; j < REC; ++j) o[j] += hk * nw2[k * REC + j];
            }
            #pragma unroll
            for (int j = 0; j < REC; ++j) o[j] = leaky(o[j]);
            if (gr >= 0) {
                float* gp = g + (size_t)gr * REC;
                #pragma unroll
                for (int j = 0; j < REC; ++j) atomicAdd(&gp[j], o[j]);
            }
            if (pp >= 0) {
                float b0 = bond_s[(size_t)pos * BOND + 0];
                float b1 = bond_s[(size_t)pos * BOND + 1];
                float b2 = bond_s[(size_t)pos * BOND + 2];
                float m[INNER];
                #pragma unroll
                for (int j = 0; j < INNER; ++j)
                    m[j] = ib[j] + b0 * iw[0 * INNER + j] + b1 * iw[1 * INNER + j]
                                 + b2 * iw[2 * INNER + j];
                #pragma unroll
                for (int k = 0; k < REC; ++k) {
                    float ok = o[k];
                    #pragma unroll
                    for (int j = 0; j < INNER; ++j) m[j] += ok * iw[(BOND + k) * INNER + j];
                }
                float4* mp = (float4*)(msg_s + (size_t)pos * REC);
                #pragma unroll
                for (int j = 0; j < 5; ++j)
                    mp[j] = make_float4(leaky(m[4*j]), leaky(m[4*j+1]),
                                        leaky(m[4*j+2]), leaky(m[4*j+3]));
            }
        }
        gbar(bar, NB * ++ep);
    }

    // ---- P21: graph readout ----
    for (int tg = tid; tg < NG; tg += GT) {
        const float* gv = g + (size_t)tg * REC;
        float gl[REC];
        #pragma unroll
        for (int k = 0; k < REC; ++k) gl[k] = gv[k];
        float acc = ob2[0];
        for (int j = 0; j < OHID; ++j) {
            float s = ob1[j];
            #pragma unroll
            for (int k = 0; k < REC; ++k) s += gl[k] * ow1[k * OHID + j];
            acc += tanhf(s) * ow2[j];
        }
        out[tg] = acc;
    }
}

extern "C" void kernel_launch(void* const* d_in, const int* in_sizes, int n_in,
                              void* d_out, int out_size, void* d_ws, size_t ws_size,
                              hipStream_t stream) {
    const float* atom    = (const float*)d_in[0];
    const float* bond    = (const float*)d_in[1];
    const int*   parent  = (const int*)d_in[2];
    const int*   child   = (const int*)d_in[3];
    const int*   depth   = (const int*)d_in[4];
    const int*   gid     = (const int*)d_in[5];
    const float* isr     = (const float*)d_in[6];
    const float* inner_w = (const float*)d_in[7];
    const float* inner_b = (const float*)d_in[8];
    const float* net_w1  = (const float*)d_in[9];
    const float* net_b1  = (const float*)d_in[10];
    const float* net_w2  = (const float*)d_in[11];
    const float* net_b2  = (const float*)d_in[12];
    const float* net0_w1 = (const float*)d_in[13];
    const float* net0_b1 = (const float*)d_in[14];
    const float* net0_w2 = (const float*)d_in[15];
    const float* net0_b2 = (const float*)d_in[16];
    const float* out_w1  = (const float*)d_in[17];
    const float* out_b1  = (const float*)d_in[18];
    const float* out_w2  = (const float*)d_in[19];
    const float* out_b2  = (const float*)d_in[20];
    float* out = (float*)d_out;

    char* ws = (char*)d_ws;
    size_t o = 0;
    float* msg_s    = (float*)(ws + o);  o += (size_t)NN * REC * 4;    // 83.9 MB
    float* g        = (float*)(ws + o);  o += (size_t)NG * REC * 4;    // 1.3 MB
    float* bond_s   = (float*)(ws + o);  o += (size_t)NN * BOND * 4;   // 12.6 MB
    int* node_list  = (int*)(ws + o);    o += (size_t)NN * 4;          // 4.2 MB
    int* inv        = (int*)(ws + o);    o += (size_t)NN * 4;          // 4.2 MB
    int* pp_s       = (int*)(ws + o);    o += (size_t)NN * 4;          // 4.2 MB
    int* rank_s     = (int*)(ws + o);    o += (size_t)NN * 4;          // 4.2 MB
    int* groot_s    = (int*)(ws + o);    o += (size_t)NN * 4;          // 4.2 MB
    int* row_ptr    = (int*)(ws + o);    o += (size_t)NN * 4;          // 4.2 MB
    int* cnt_pos    = (int*)(ws + o);    o += (size_t)NN * 4;          // 4.2 MB
    int* adjc       = (int*)(ws + o);    o += (size_t)NE * 4;          // 3.9 MB
    unsigned char* hc = (unsigned char*)(ws + o); o += (size_t)NN;     // 1.0 MB
    int* blkbase    = (int*)(ws + o);    o += (size_t)NB * NBIN * 4;   // 64 KB
    int* cnt16      = (int*)(ws + o);    o += NBIN * 16 * 4;           // padded
    int* adj_total  = (int*)(ws + o);    o += 64;
    int* bar        = (int*)(ws + o);    o += 256;
    // total ~136 MB

    k_pre<<<256, 256, 0, stream>>>((int*)hc, cnt16, adj_total, bar);
    k_fused<<<NB, NT, 0, stream>>>(atom, bond, parent, child, depth, gid, isr,
                                   inner_w, inner_b, net_w1, net_b1, net_w2, net_b2,
                                   net0_w1, net0_b1, net0_w2, net0_b2,
                                   out_w1, out_b1, out_w2, out_b2, out,
                                   msg_s, g, bond_s, node_list, inv, pp_s, rank_s,
                                   groot_s, row_ptr, cnt_pos, adjc,
                                   hc, blkbase, cnt16, adj_total, bar);
}